// Round 2
// baseline (446.250 us; speedup 1.0000x reference)
//
#include <hip/hip_runtime.h>

// out = clip(x + laplace_noise * mask, 0, 1), element-wise over
// N = 256*3*224*224 = 38,535,168 fp32 elements. Memory-bound streaming.
//
// v2 (re-run; previous bench was an infra failure, kernel never executed):
// ILP=4 — each thread processes 4 block-strided float4s per stream,
// issuing 12 independent 16B loads before any use. Cuts wave count 4x
// (150,528 -> 37,632 waves) to fix the wave-turnover MLP limit seen at
// 155 us/dispatch (2.5 TB/s HBM, 4.0 TB/s effective). Output is stored
// non-temporally: it is never re-read, so keep L3 capacity for the input
// streams (which L3 currently serves at ~50% hit rate).

typedef float f4 __attribute__((ext_vector_type(4)));

constexpr int BLOCK = 256;
constexpr int ILP   = 4;   // float4s per thread per stream

__global__ __launch_bounds__(BLOCK) void rrn_clip_kernel(
    const f4* __restrict__ x,
    const f4* __restrict__ lap,
    const f4* __restrict__ mask,
    f4* __restrict__ out,
    int n4)
{
    const int i0 = blockIdx.x * (BLOCK * ILP) + threadIdx.x;

    int idx[ILP];
#pragma unroll
    for (int k = 0; k < ILP; ++k) idx[k] = i0 + k * BLOCK;

    if (idx[ILP - 1] < n4) {
        // Fast path: all ILP accesses in-bounds (always taken at this
        // problem size: n4 = 9,633,792 = 9408 * 1024 exactly).
        f4 xv[ILP], lv[ILP], mv[ILP];
#pragma unroll
        for (int k = 0; k < ILP; ++k) xv[k] = x[idx[k]];
#pragma unroll
        for (int k = 0; k < ILP; ++k) lv[k] = lap[idx[k]];
#pragma unroll
        for (int k = 0; k < ILP; ++k) mv[k] = mask[idx[k]];

#pragma unroll
        for (int k = 0; k < ILP; ++k) {
            f4 o;
            o.x = fminf(fmaxf(fmaf(lv[k].x, mv[k].x, xv[k].x), 0.0f), 1.0f);
            o.y = fminf(fmaxf(fmaf(lv[k].y, mv[k].y, xv[k].y), 0.0f), 1.0f);
            o.z = fminf(fmaxf(fmaf(lv[k].z, mv[k].z, xv[k].z), 0.0f), 1.0f);
            o.w = fminf(fmaxf(fmaf(lv[k].w, mv[k].w, xv[k].w), 0.0f), 1.0f);
            __builtin_nontemporal_store(o, &out[idx[k]]);
        }
    } else {
        // Tail path (never taken at this size, kept for safety).
#pragma unroll
        for (int k = 0; k < ILP; ++k) {
            if (idx[k] < n4) {
                f4 xv = x[idx[k]];
                f4 lv = lap[idx[k]];
                f4 mv = mask[idx[k]];
                f4 o;
                o.x = fminf(fmaxf(fmaf(lv.x, mv.x, xv.x), 0.0f), 1.0f);
                o.y = fminf(fmaxf(fmaf(lv.y, mv.y, xv.y), 0.0f), 1.0f);
                o.z = fminf(fmaxf(fmaf(lv.z, mv.z, xv.z), 0.0f), 1.0f);
                o.w = fminf(fmaxf(fmaf(lv.w, mv.w, xv.w), 0.0f), 1.0f);
                __builtin_nontemporal_store(o, &out[idx[k]]);
            }
        }
    }
}

extern "C" void kernel_launch(void* const* d_in, const int* in_sizes, int n_in,
                              void* d_out, int out_size, void* d_ws, size_t ws_size,
                              hipStream_t stream)
{
    const f4* x    = (const f4*)d_in[0];
    // d_in[1] = eps (scalar) — unused; Bernoulli keep-prob already in mask.
    const f4* lap  = (const f4*)d_in[2];
    const f4* mask = (const f4*)d_in[3];
    f4* out        = (f4*)d_out;

    int n  = out_size;           // 38,535,168 — divisible by 16
    int n4 = n >> 2;             // 9,633,792 float4 elements

    const int per_block = BLOCK * ILP;                  // 1024 float4s / block
    const int grid = (n4 + per_block - 1) / per_block;  // 9408 blocks

    rrn_clip_kernel<<<grid, BLOCK, 0, stream>>>(x, lap, mask, out, n4);
}